// Round 8
// baseline (101.170 us; speedup 1.0000x reference)
//
#include <hip/hip_runtime.h>

#define NQ 10
#define NL 5

typedef float v2f __attribute__((ext_vector_type(2)));

__device__ __forceinline__ v2f sp(float s) { v2f r = { s, s }; return r; }

// ---- cross-lane xor exchange (direct-partner masks) ----
// xor 1,2,8: DPP (VALU). xor 4: ds_swizzle.
template <int M>
__device__ __forceinline__ float lane_xor_direct(float v) {
    unsigned u = __float_as_uint(v);
    if constexpr (M == 1) {        // quad_perm [1,0,3,2]
        return __uint_as_float((unsigned)__builtin_amdgcn_update_dpp(0, (int)u, 0xB1, 0xF, 0xF, true));
    } else if constexpr (M == 2) { // quad_perm [2,3,0,1]
        return __uint_as_float((unsigned)__builtin_amdgcn_update_dpp(0, (int)u, 0x4E, 0xF, 0xF, true));
    } else if constexpr (M == 4) { // ds_swizzle BitMode xor=4
        return __uint_as_float((unsigned)__builtin_amdgcn_ds_swizzle((int)u, 0x101F));
    } else {                       // M == 8: row_ror:8 == xor8 within 16
        return __uint_as_float((unsigned)__builtin_amdgcn_update_dpp(0, (int)u, 0x128, 0xF, 0xF, true));
    }
}

// xor 16 / 32: permlane*_swap returns both rows; r0 = "vdst" half, r1 = "src" half.
// partner = (lane&M) ? r0 : r1 ; own stays in v.
template <int M>
__device__ __forceinline__ void lane_swap_pair(float v, float& r0, float& r1) {
    unsigned u = __float_as_uint(v);
    if constexpr (M == 16) {
        auto r = __builtin_amdgcn_permlane16_swap(u, u, false, false);
        r0 = __uint_as_float(r[0]); r1 = __uint_as_float(r[1]);
    } else {
        auto r = __builtin_amdgcn_permlane32_swap(u, u, false, false);
        r0 = __uint_as_float(r[0]); r1 = __uint_as_float(r[1]);
    }
}

// generic xor for the final reduction
template <int M>
__device__ __forceinline__ float lane_xor(float v, int lane) {
    if constexpr (M < 16) {
        return lane_xor_direct<M>(v);
    } else {
        float r0, r1;
        lane_swap_pair<M>(v, r0, r1);
        return (lane & M) ? r0 : r1;
    }
}

// U = Rz(tz) @ Ry(ty) @ Rx(tx)  (SU(2): u11 = conj(u00), u10 = -conj(u01))
__device__ __forceinline__ void make_u(float tx, float ty, float tz,
                                       float& u00r, float& u00i, float& u01r, float& u01i,
                                       float& u10r, float& u10i, float& u11r, float& u11i) {
    float cx, sx, cy, sy, cz, sz;
    __sincosf(0.5f * tx, &sx, &cx);
    __sincosf(0.5f * ty, &sy, &cy);
    __sincosf(0.5f * tz, &sz, &cz);
    u00r =  cz * cy * cx + sz * sy * sx;
    u00i =  cz * sy * sx - sz * cy * cx;
    u01r = -cz * sy * cx - sz * cy * sx;
    u01i =  sz * sy * cx - cz * cy * sx;
    u10r = -u01r;  u10i =  u01i;
    u11r =  u00r;  u11i = -u00i;
}

// Setup: 60 gate matrices. gm[g*16+0..7] = V0 = U ; gm[g*16+8..15] = V1 = -i*U*X.
__global__ void pqc_setup(const float* __restrict__ theta, float* __restrict__ gm) {
    int g = threadIdx.x;
    if (g >= (NL + 1) * NQ) return;
    const float* th = theta + g * 3;
    float u00r, u00i, u01r, u01i, u10r, u10i, u11r, u11i;
    make_u(th[0], th[1], th[2], u00r, u00i, u01r, u01i, u10r, u10i, u11r, u11i);
    float* o = gm + g * 16;
    o[0] = u00r;  o[1] = u00i;  o[2] = u01r;  o[3] = u01i;
    o[4] = u10r;  o[5] = u10i;  o[6] = u11r;  o[7] = u11i;
    o[8]  = u01i; o[9]  = -u01r; o[10] = u00i; o[11] = -u00r;
    o[12] = u11i; o[13] = -u11r; o[14] = u10i; o[15] = -u10r;
}

// State: amplitude k = lane*16 + r, r = 2*j + h.  fr[j]/fi[j] hold re/im of (r=2j, r=2j+1).
// Bit P of k: P=0 -> h (in v2f), P=1..3 -> j bits, P=4..9 -> lane bits.
template <int P>
__device__ __forceinline__ void apply_p(v2f fr[8], v2f fi[8], const float wv[8], int lane) {
    const float w00r = wv[0], w00i = wv[1], w01r = wv[2], w01i = wv[3];
    const float w10r = wv[4], w10i = wv[5], w11r = wv[6], w11i = wv[7];
    if constexpr (P == 0) {
        v2f c0r = { w00r, w11r }, c0i = { w00i, w11i };
        v2f c1r = { w01r, w10r }, c1i = { w01i, w10i };
#pragma unroll
        for (int j = 0; j < 8; ++j) {
            v2f ar = fr[j], ai = fi[j];
            v2f srp = ar.yx, sip = ai.yx;
            fr[j] = c0r * ar - c0i * ai + c1r * srp - c1i * sip;
            fi[j] = c0r * ai + c0i * ar + c1r * sip + c1i * srp;
        }
    } else if constexpr (P < 4) {
        constexpr int LJ = 1 << (P - 1);
        v2f a00r = sp(w00r), a00i = sp(w00i), a01r = sp(w01r), a01i = sp(w01i);
        v2f a10r = sp(w10r), a10i = sp(w10i), a11r = sp(w11r), a11i = sp(w11i);
#pragma unroll
        for (int base = 0; base < 8; ++base) {
            if (base & LJ) continue;
            v2f a0r = fr[base], a0i = fi[base];
            v2f a1r = fr[base | LJ], a1i = fi[base | LJ];
            fr[base]      = a00r * a0r - a00i * a0i + a01r * a1r - a01i * a1i;
            fi[base]      = a00r * a0i + a00i * a0r + a01r * a1i + a01i * a1r;
            fr[base | LJ] = a10r * a0r - a10i * a0i + a11r * a1r - a11i * a1i;
            fi[base | LJ] = a10r * a0i + a10i * a0r + a11r * a1i + a11i * a1r;
        }
    } else if constexpr (P < 8) {
        constexpr int M = 1 << (P - 4);
        const int bit = (lane >> (P - 4)) & 1;
        v2f pr = sp(bit ? w11r : w00r), pi = sp(bit ? w11i : w00i);
        v2f qr = sp(bit ? w10r : w01r), qi = sp(bit ? w10i : w01i);
#pragma unroll
        for (int j = 0; j < 8; ++j) {
            v2f ofr, ofi;
            ofr.x = lane_xor_direct<M>(fr[j].x);
            ofr.y = lane_xor_direct<M>(fr[j].y);
            ofi.x = lane_xor_direct<M>(fi[j].x);
            ofi.y = lane_xor_direct<M>(fi[j].y);
            v2f nr = pr * fr[j] - pi * fi[j] + qr * ofr - qi * ofi;
            v2f ni = pr * fi[j] + pi * fr[j] + qr * ofi + qi * ofr;
            fr[j] = nr;
            fi[j] = ni;
        }
    } else {
        // P = 8,9 -> lane xor 16/32 via permlane swap: result = cA*r0 + cB*r1,
        // cA = (hi ? w10 : w00), cB = (hi ? w11 : w01) — no per-value selects.
        constexpr int M = 1 << (P - 4);
        const bool hi = (lane & M) != 0;
        v2f cAr = sp(hi ? w10r : w00r), cAi = sp(hi ? w10i : w00i);
        v2f cBr = sp(hi ? w11r : w01r), cBi = sp(hi ? w11i : w01i);
#pragma unroll
        for (int j = 0; j < 8; ++j) {
            float a0x, a1x, a0y, a1y, b0x, b1x, b0y, b1y;
            lane_swap_pair<M>(fr[j].x, a0x, a1x);
            lane_swap_pair<M>(fr[j].y, a0y, a1y);
            lane_swap_pair<M>(fi[j].x, b0x, b1x);
            lane_swap_pair<M>(fi[j].y, b0y, b1y);
            v2f A0r = { a0x, a0y }, A1r = { a1x, a1y };
            v2f A0i = { b0x, b0y }, A1i = { b1x, b1y };
            fr[j] = cAr * A0r - cAi * A0i + cBr * A1r - cBi * A1i;
            fi[j] = cAr * A0i + cAi * A0r + cBr * A1i + cBi * A1r;
        }
    }
}

// Two elements per wave: per qubit build W for both, apply to both (independent streams).
#define GATE2(qq, PP)                                                              \
    {                                                                              \
        const float* g = gl + (qq) * 16;                                           \
        float W0[8], W1[8];                                                        \
        _Pragma("unroll")                                                          \
        for (int t = 0; t < 8; ++t) {                                              \
            W0[t] = cc0[qq] * g[t] + ss0[qq] * g[8 + t];                           \
            W1[t] = cc1[qq] * g[t] + ss1[qq] * g[8 + t];                           \
        }                                                                          \
        apply_p<PP>(fr0, fi0, W0, lane);                                           \
        apply_p<PP>(fr1, fi1, W1, lane);                                           \
    }

__global__ void __launch_bounds__(64, 2) pqc_kernel(const float* __restrict__ x,
                                                    const float* __restrict__ lam,
                                                    const float* __restrict__ w,
                                                    const float* __restrict__ gm,
                                                    float* __restrict__ out, int B) {
    const int lane = threadIdx.x;
    const int b0 = blockIdx.x * 2;
    const int b1 = b0 + 1;

    v2f fr0[8], fi0[8], fr1[8], fi1[8];
#pragma unroll
    for (int j = 0; j < 8; ++j) {
        fr0[j] = sp(0.f); fi0[j] = sp(0.f);
        fr1[j] = sp(0.f); fi1[j] = sp(0.f);
    }
    if (lane == 0) { fr0[0].x = 1.f; fr1[0].x = 1.f; }

    // CZ-ring sign vectors and Z^n parity mask (shared by both elements).
    v2f sv[8];
    unsigned zmask = 0;
#pragma unroll
    for (int j = 0; j < 8; ++j) {
#pragma unroll
        for (int h = 0; h < 2; ++h) {
            int k = (lane << 4) | (2 * j + h);
            int par = (__popc(k & (k >> 1)) + ((k & (k >> 9)) & 1)) & 1;
            float s = __uint_as_float(0x3f800000u | ((unsigned)par << 31));
            if (h == 0) sv[j].x = s; else sv[j].y = s;
            zmask |= (unsigned)(__popc(k) & 1) << (2 * j + h);
        }
    }

    float xr0[NQ], xr1[NQ];
#pragma unroll
    for (int q = 0; q < NQ; ++q) {
        xr0[q] = x[b0 * NQ + q];
        xr1[q] = x[b1 * NQ + q];
    }

    // Dynamic layer loop (I-cache-friendly). Layer 0: sincos(0) = (0,1) -> W = V0 exactly.
    for (int l = 0; l <= NL; ++l) {
        const float* gl = gm + l * NQ * 16;
        const float* lm = lam + (l > 0 ? (l - 1) * NQ : 0);
        const float en = (l > 0) ? 0.5f : 0.0f;
        float cc0[NQ], ss0[NQ], cc1[NQ], ss1[NQ];
#pragma unroll
        for (int q = 0; q < NQ; ++q) {
            __sincosf(en * xr0[q] * lm[q], &ss0[q], &cc0[q]);
            __sincosf(en * xr1[q] * lm[q], &ss1[q], &cc1[q]);
        }
        // wire q acts on bit 9-q
        GATE2(0, 9) GATE2(1, 8) GATE2(2, 7) GATE2(3, 6) GATE2(4, 5)
        GATE2(5, 4) GATE2(6, 3) GATE2(7, 2) GATE2(8, 1) GATE2(9, 0)
#pragma unroll
        for (int j = 0; j < 8; ++j) {
            fr0[j] *= sv[j]; fi0[j] *= sv[j];
            fr1[j] *= sv[j]; fi1[j] *= sv[j];
        }
    }

    // <Z^n> = sum |amp|^2 * (-1)^popcount(k), both elements.
    v2f acc0 = sp(0.f), acc1 = sp(0.f);
#pragma unroll
    for (int j = 0; j < 8; ++j) {
        v2f zs;
        zs.x = __uint_as_float(0x3f800000u | (((zmask >> (2 * j)) & 1u) << 31));
        zs.y = __uint_as_float(0x3f800000u | (((zmask >> (2 * j + 1)) & 1u) << 31));
        acc0 += zs * (fr0[j] * fr0[j] + fi0[j] * fi0[j]);
        acc1 += zs * (fr1[j] * fr1[j] + fi1[j] * fi1[j]);
    }
    float ez0 = acc0.x + acc0.y;
    float ez1 = acc1.x + acc1.y;
    ez0 += lane_xor<1>(ez0, lane);   ez1 += lane_xor<1>(ez1, lane);
    ez0 += lane_xor<2>(ez0, lane);   ez1 += lane_xor<2>(ez1, lane);
    ez0 += lane_xor<4>(ez0, lane);   ez1 += lane_xor<4>(ez1, lane);
    ez0 += lane_xor<8>(ez0, lane);   ez1 += lane_xor<8>(ez1, lane);
    ez0 += lane_xor<16>(ez0, lane);  ez1 += lane_xor<16>(ez1, lane);
    ez0 += lane_xor<32>(ez0, lane);  ez1 += lane_xor<32>(ez1, lane);

    if (lane == 0) {
        float w0 = w[0], w1 = w[1];             // BETA = 1
        {
            float l0 = ez0 * w0, l1 = ez0 * w1;
            float m = fmaxf(l0, l1);
            float e0 = __expf(l0 - m), e1 = __expf(l1 - m);
            float inv = 1.f / (e0 + e1);
            out[2 * b0 + 0] = e0 * inv;
            out[2 * b0 + 1] = e1 * inv;
        }
        {
            float l0 = ez1 * w0, l1 = ez1 * w1;
            float m = fmaxf(l0, l1);
            float e0 = __expf(l0 - m), e1 = __expf(l1 - m);
            float inv = 1.f / (e0 + e1);
            out[2 * b1 + 0] = e0 * inv;
            out[2 * b1 + 1] = e1 * inv;
        }
    }
}

extern "C" void kernel_launch(void* const* d_in, const int* in_sizes, int n_in,
                              void* d_out, int out_size, void* d_ws, size_t ws_size,
                              hipStream_t stream) {
    const float* x     = (const float*)d_in[0];
    const float* theta = (const float*)d_in[1];
    const float* lam   = (const float*)d_in[2];
    const float* w     = (const float*)d_in[3];
    float* out = (float*)d_out;
    float* gm  = (float*)d_ws;                 // 60 gates * 16 floats = 3840 B

    const int B = in_sizes[0] / NQ;            // 2048
    hipLaunchKernelGGL(pqc_setup, dim3(1), dim3(64), 0, stream, theta, gm);
    hipLaunchKernelGGL(pqc_kernel, dim3(B / 2), dim3(64), 0, stream,
                       x, lam, w, gm, out, B);
}

// Round 10
// 90.139 us; speedup vs baseline: 1.1224x; 1.1224x over previous
//
#include <hip/hip_runtime.h>

#define NQ 10
#define NL 5

typedef float v2f __attribute__((ext_vector_type(2)));

__device__ __forceinline__ v2f sp(float s) { v2f r = { s, s }; return r; }

// ---- cross-lane xor exchange (direct-partner masks), all VALU ----
// xor 1,2,8: single DPP. xor 4: two bank-masked DPP row shifts (no DS pipe).
// ISA semantics (GCN DPP table): ROW_SHL:N -> dst[i] = src[i+N] (zero from the right);
// ROW_SHR:N -> dst[i] = src[i-N] (zero from the left). row_ror:8 is direction-symmetric.
template <int M>
__device__ __forceinline__ float lane_xor_direct(float v) {
    unsigned u = __float_as_uint(v);
    if constexpr (M == 1) {        // quad_perm [1,0,3,2]
        return __uint_as_float((unsigned)__builtin_amdgcn_update_dpp(0, (int)u, 0xB1, 0xF, 0xF, true));
    } else if constexpr (M == 2) { // quad_perm [2,3,0,1]
        return __uint_as_float((unsigned)__builtin_amdgcn_update_dpp(0, (int)u, 0x4E, 0xF, 0xF, true));
    } else if constexpr (M == 4) {
        // banks 0,2 (lanes i&4==0) need src[i+4] -> ROW_SHL:4 (0x104)
        // banks 1,3 (lanes i&4==4) need src[i-4] -> ROW_SHR:4 (0x114)
        int t = __builtin_amdgcn_update_dpp(0, (int)u, 0x104, 0xF, 0x5, false);
        t     = __builtin_amdgcn_update_dpp(t, (int)u, 0x114, 0xF, 0xA, false);
        return __uint_as_float((unsigned)t);
    } else {                       // M == 8: row_ror:8 == xor8 within 16
        return __uint_as_float((unsigned)__builtin_amdgcn_update_dpp(0, (int)u, 0x128, 0xF, 0xF, true));
    }
}

// xor 16 / 32: permlane*_swap returns both rows; partner = (lane&M) ? r[0] : r[1].
template <int M>
__device__ __forceinline__ void lane_swap_pair(float v, float& r0, float& r1) {
    unsigned u = __float_as_uint(v);
    if constexpr (M == 16) {
        auto r = __builtin_amdgcn_permlane16_swap(u, u, false, false);
        r0 = __uint_as_float(r[0]); r1 = __uint_as_float(r[1]);
    } else {
        auto r = __builtin_amdgcn_permlane32_swap(u, u, false, false);
        r0 = __uint_as_float(r[0]); r1 = __uint_as_float(r[1]);
    }
}

template <int M>
__device__ __forceinline__ float lane_xor(float v, int lane) {
    if constexpr (M < 16) {
        return lane_xor_direct<M>(v);
    } else {
        float r0, r1;
        lane_swap_pair<M>(v, r0, r1);
        return (lane & M) ? r0 : r1;
    }
}

// U = Rz(tz) @ Ry(ty) @ Rx(tx)  (SU(2): u11 = conj(u00), u10 = -conj(u01))
__device__ __forceinline__ void make_u(float tx, float ty, float tz,
                                       float& u00r, float& u00i, float& u01r, float& u01i,
                                       float& u10r, float& u10i, float& u11r, float& u11i) {
    float cx, sx, cy, sy, cz, sz;
    __sincosf(0.5f * tx, &sx, &cx);
    __sincosf(0.5f * ty, &sy, &cy);
    __sincosf(0.5f * tz, &sz, &cz);
    u00r =  cz * cy * cx + sz * sy * sx;
    u00i =  cz * sy * sx - sz * cy * cx;
    u01r = -cz * sy * cx - sz * cy * sx;
    u01i =  sz * sy * cx - cz * cy * sx;
    u10r = -u01r;  u10i =  u01i;
    u11r =  u00r;  u11i = -u00i;
}

// Setup: 60 gate matrices. gm[g*16+0..7] = V0 = U ; gm[g*16+8..15] = V1 = -i*U*X.
__global__ void pqc_setup(const float* __restrict__ theta, float* __restrict__ gm) {
    int g = threadIdx.x;
    if (g >= (NL + 1) * NQ) return;
    const float* th = theta + g * 3;
    float u00r, u00i, u01r, u01i, u10r, u10i, u11r, u11i;
    make_u(th[0], th[1], th[2], u00r, u00i, u01r, u01i, u10r, u10i, u11r, u11i);
    float* o = gm + g * 16;
    o[0] = u00r;  o[1] = u00i;  o[2] = u01r;  o[3] = u01i;
    o[4] = u10r;  o[5] = u10i;  o[6] = u11r;  o[7] = u11i;
    o[8]  = u01i; o[9]  = -u01r; o[10] = u00i; o[11] = -u00r;
    o[12] = u11i; o[13] = -u11r; o[14] = u10i; o[15] = -u10r;
}

// State: amplitude k = lane*16 + r, r = 2*j + h.  fr[j]/fi[j] hold re/im of (r=2j, r=2j+1).
// Bit P of k: P=0 -> h (in v2f), P=1..3 -> j bits, P=4..9 -> lane bits.
template <int P>
__device__ __forceinline__ void apply_p(v2f fr[8], v2f fi[8], const float wv[8], int lane) {
    const float w00r = wv[0], w00i = wv[1], w01r = wv[2], w01i = wv[3];
    const float w10r = wv[4], w10i = wv[5], w11r = wv[6], w11i = wv[7];
    if constexpr (P == 0) {
        v2f c0r = { w00r, w11r }, c0i = { w00i, w11i };
        v2f c1r = { w01r, w10r }, c1i = { w01i, w10i };
#pragma unroll
        for (int j = 0; j < 8; ++j) {
            v2f ar = fr[j], ai = fi[j];
            v2f srp = ar.yx, sip = ai.yx;
            fr[j] = c0r * ar - c0i * ai + c1r * srp - c1i * sip;
            fi[j] = c0r * ai + c0i * ar + c1r * sip + c1i * srp;
        }
    } else if constexpr (P < 4) {
        constexpr int LJ = 1 << (P - 1);
        v2f a00r = sp(w00r), a00i = sp(w00i), a01r = sp(w01r), a01i = sp(w01i);
        v2f a10r = sp(w10r), a10i = sp(w10i), a11r = sp(w11r), a11i = sp(w11i);
#pragma unroll
        for (int base = 0; base < 8; ++base) {
            if (base & LJ) continue;
            v2f a0r = fr[base], a0i = fi[base];
            v2f a1r = fr[base | LJ], a1i = fi[base | LJ];
            fr[base]      = a00r * a0r - a00i * a0i + a01r * a1r - a01i * a1i;
            fi[base]      = a00r * a0i + a00i * a0r + a01r * a1i + a01i * a1r;
            fr[base | LJ] = a10r * a0r - a10i * a0i + a11r * a1r - a11i * a1i;
            fi[base | LJ] = a10r * a0i + a10i * a0r + a11r * a1i + a11i * a1r;
        }
    } else if constexpr (P < 8) {
        constexpr int M = 1 << (P - 4);
        const int bit = (lane >> (P - 4)) & 1;
        v2f pr = sp(bit ? w11r : w00r), pi = sp(bit ? w11i : w00i);
        v2f qr = sp(bit ? w10r : w01r), qi = sp(bit ? w10i : w01i);
#pragma unroll
        for (int j = 0; j < 8; ++j) {
            v2f ofr, ofi;
            ofr.x = lane_xor_direct<M>(fr[j].x);
            ofr.y = lane_xor_direct<M>(fr[j].y);
            ofi.x = lane_xor_direct<M>(fi[j].x);
            ofi.y = lane_xor_direct<M>(fi[j].y);
            v2f nr = pr * fr[j] - pi * fi[j] + qr * ofr - qi * ofi;
            v2f ni = pr * fi[j] + pi * fr[j] + qr * ofi + qi * ofr;
            fr[j] = nr;
            fi[j] = ni;
        }
    } else {
        // P = 8,9 -> permlane swap gives both halves: result = cA*r0 + cB*r1, no selects.
        constexpr int M = 1 << (P - 4);
        const bool hi = (lane & M) != 0;
        v2f cAr = sp(hi ? w10r : w00r), cAi = sp(hi ? w10i : w00i);
        v2f cBr = sp(hi ? w11r : w01r), cBi = sp(hi ? w11i : w01i);
#pragma unroll
        for (int j = 0; j < 8; ++j) {
            float a0x, a1x, a0y, a1y, b0x, b1x, b0y, b1y;
            lane_swap_pair<M>(fr[j].x, a0x, a1x);
            lane_swap_pair<M>(fr[j].y, a0y, a1y);
            lane_swap_pair<M>(fi[j].x, b0x, b1x);
            lane_swap_pair<M>(fi[j].y, b0y, b1y);
            v2f A0r = { a0x, a0y }, A1r = { a1x, a1y };
            v2f A0i = { b0x, b0y }, A1i = { b1x, b1y };
            fr[j] = cAr * A0r - cAi * A0i + cBr * A1r - cBi * A1i;
            fi[j] = cAr * A0i + cAi * A0r + cBr * A1i + cBi * A1r;
        }
    }
}

// One gate: W = c*V0 + s*V1 built with packed v2f FMAs (8 pk ops), then apply.
#define GATE(qq, PP)                                                               \
    {                                                                              \
        const float* g = gl + (qq) * 16;                                           \
        v2f c = sp(cc[qq]), s = sp(ss[qq]);                                        \
        v2f w0 = c * *(const v2f*)(g + 0) + s * *(const v2f*)(g + 8);              \
        v2f w1 = c * *(const v2f*)(g + 2) + s * *(const v2f*)(g + 10);             \
        v2f w2 = c * *(const v2f*)(g + 4) + s * *(const v2f*)(g + 12);             \
        v2f w3 = c * *(const v2f*)(g + 6) + s * *(const v2f*)(g + 14);             \
        const float W[8] = { w0.x, w0.y, w1.x, w1.y, w2.x, w2.y, w3.x, w3.y };     \
        apply_p<PP>(fr, fi, W, lane);                                              \
    }

// One wave per element, 2048 waves (2/SIMD). Dynamic layer loop keeps the body
// I-cache-resident (~1 layer of code, not 6). Layer 0: en=0 -> sincos(0)=(0,1) -> W=V0.
__global__ void __launch_bounds__(64, 2) pqc_kernel(const float* __restrict__ x,
                                                    const float* __restrict__ lam,
                                                    const float* __restrict__ w,
                                                    const float* __restrict__ gm,
                                                    float* __restrict__ out, int B) {
    const int lane = threadIdx.x;
    const int b = blockIdx.x;

    v2f fr[8], fi[8];
#pragma unroll
    for (int j = 0; j < 8; ++j) { fr[j] = sp(0.f); fi[j] = sp(0.f); }
    if (lane == 0) fr[0].x = 1.f;

    // CZ-ring sign vectors and Z^n parity mask for this lane's 16 amplitudes.
    v2f sv[8];
    unsigned zmask = 0;
#pragma unroll
    for (int j = 0; j < 8; ++j) {
#pragma unroll
        for (int h = 0; h < 2; ++h) {
            int k = (lane << 4) | (2 * j + h);
            int par = (__popc(k & (k >> 1)) + ((k & (k >> 9)) & 1)) & 1;
            float s = __uint_as_float(0x3f800000u | ((unsigned)par << 31));
            if (h == 0) sv[j].x = s; else sv[j].y = s;
            zmask |= (unsigned)(__popc(k) & 1) << (2 * j + h);
        }
    }

    float xr[NQ];
#pragma unroll
    for (int q = 0; q < NQ; ++q) xr[q] = x[b * NQ + q];

#pragma clang loop unroll(disable)
    for (int l = 0; l <= NL; ++l) {
        const float* gl = gm + l * NQ * 16;
        const float* lm = lam + (l > 0 ? (l - 1) * NQ : 0);
        const float en = (l > 0) ? 0.5f : 0.0f;
        float cc[NQ], ss[NQ];
#pragma unroll
        for (int q = 0; q < NQ; ++q)
            __sincosf(en * xr[q] * lm[q], &ss[q], &cc[q]);
        // wire q acts on bit 9-q
        GATE(0, 9) GATE(1, 8) GATE(2, 7) GATE(3, 6) GATE(4, 5)
        GATE(5, 4) GATE(6, 3) GATE(7, 2) GATE(8, 1) GATE(9, 0)
#pragma unroll
        for (int j = 0; j < 8; ++j) { fr[j] *= sv[j]; fi[j] *= sv[j]; }
    }

    // <Z^n> = sum |amp|^2 * (-1)^popcount(k)
    v2f acc = sp(0.f);
#pragma unroll
    for (int j = 0; j < 8; ++j) {
        v2f zs;
        zs.x = __uint_as_float(0x3f800000u | (((zmask >> (2 * j)) & 1u) << 31));
        zs.y = __uint_as_float(0x3f800000u | (((zmask >> (2 * j + 1)) & 1u) << 31));
        acc += zs * (fr[j] * fr[j] + fi[j] * fi[j]);
    }
    float ez = acc.x + acc.y;
    ez += lane_xor<1>(ez, lane);
    ez += lane_xor<2>(ez, lane);
    ez += lane_xor<4>(ez, lane);
    ez += lane_xor<8>(ez, lane);
    ez += lane_xor<16>(ez, lane);
    ez += lane_xor<32>(ez, lane);

    if (lane == 0) {
        float l0 = ez * w[0], l1 = ez * w[1];   // BETA = 1
        float m = fmaxf(l0, l1);
        float e0 = __expf(l0 - m), e1 = __expf(l1 - m);
        float inv = 1.f / (e0 + e1);
        out[2 * b + 0] = e0 * inv;
        out[2 * b + 1] = e1 * inv;
    }
}

extern "C" void kernel_launch(void* const* d_in, const int* in_sizes, int n_in,
                              void* d_out, int out_size, void* d_ws, size_t ws_size,
                              hipStream_t stream) {
    const float* x     = (const float*)d_in[0];
    const float* theta = (const float*)d_in[1];
    const float* lam   = (const float*)d_in[2];
    const float* w     = (const float*)d_in[3];
    float* out = (float*)d_out;
    float* gm  = (float*)d_ws;                 // 60 gates * 16 floats = 3840 B

    const int B = in_sizes[0] / NQ;            // 2048
    hipLaunchKernelGGL(pqc_setup, dim3(1), dim3(64), 0, stream, theta, gm);
    hipLaunchKernelGGL(pqc_kernel, dim3(B), dim3(64), 0, stream,
                       x, lam, w, gm, out, B);
}

// Round 11
// 85.582 us; speedup vs baseline: 1.1821x; 1.0532x over previous
//
#include <hip/hip_runtime.h>

#define NQ 10
#define NL 5

typedef float v2f __attribute__((ext_vector_type(2)));

__device__ __forceinline__ v2f sp(float s) { v2f r = { s, s }; return r; }

// ---- cross-lane xor exchange (direct-partner masks), all VALU ----
template <int M>
__device__ __forceinline__ float lane_xor_direct(float v) {
    unsigned u = __float_as_uint(v);
    if constexpr (M == 1) {        // quad_perm [1,0,3,2]
        return __uint_as_float((unsigned)__builtin_amdgcn_update_dpp(0, (int)u, 0xB1, 0xF, 0xF, true));
    } else if constexpr (M == 2) { // quad_perm [2,3,0,1]
        return __uint_as_float((unsigned)__builtin_amdgcn_update_dpp(0, (int)u, 0x4E, 0xF, 0xF, true));
    } else if constexpr (M == 4) {
        // lanes i&4==0 need src[i+4] -> ROW_SHL:4; lanes i&4==4 need src[i-4] -> ROW_SHR:4
        int t = __builtin_amdgcn_update_dpp(0, (int)u, 0x104, 0xF, 0x5, false);
        t     = __builtin_amdgcn_update_dpp(t, (int)u, 0x114, 0xF, 0xA, false);
        return __uint_as_float((unsigned)t);
    } else {                       // M == 8: row_ror:8 == xor8 within 16
        return __uint_as_float((unsigned)__builtin_amdgcn_update_dpp(0, (int)u, 0x128, 0xF, 0xF, true));
    }
}

template <int M>
__device__ __forceinline__ void lane_swap_pair(float v, float& r0, float& r1) {
    unsigned u = __float_as_uint(v);
    if constexpr (M == 16) {
        auto r = __builtin_amdgcn_permlane16_swap(u, u, false, false);
        r0 = __uint_as_float(r[0]); r1 = __uint_as_float(r[1]);
    } else {
        auto r = __builtin_amdgcn_permlane32_swap(u, u, false, false);
        r0 = __uint_as_float(r[0]); r1 = __uint_as_float(r[1]);
    }
}

template <int M>
__device__ __forceinline__ float lane_xor(float v, int lane) {
    if constexpr (M < 16) {
        return lane_xor_direct<M>(v);
    } else {
        float r0, r1;
        lane_swap_pair<M>(v, r0, r1);
        return (lane & M) ? r0 : r1;
    }
}

// U = Rz(tz) @ Ry(ty) @ Rx(tx)  (SU(2): u11 = conj(u00), u10 = -conj(u01))
__device__ __forceinline__ void make_u(float tx, float ty, float tz,
                                       float& u00r, float& u00i, float& u01r, float& u01i) {
    float cx, sx, cy, sy, cz, sz;
    __sincosf(0.5f * tx, &sx, &cx);
    __sincosf(0.5f * ty, &sy, &cy);
    __sincosf(0.5f * tz, &sz, &cz);
    u00r =  cz * cy * cx + sz * sy * sx;
    u00i =  cz * sy * sx - sz * cy * cx;
    u01r = -cz * sy * cx - sz * cy * sx;
    u01i =  sz * sy * cx - cz * cy * sx;
}

// Setup: 60 gates x 8 floats. W(t) = c*V0 + s*V1 is SU(2): only the top row
// (w00, w01) is needed; w10 = -conj(w01), w11 = conj(w00).
// g[0..3] = (u00r,u00i,u01r,u01i) ; g[4..7] = V1 top row = (u01i,-u01r,u00i,-u00r).
__global__ void pqc_setup(const float* __restrict__ theta, float* __restrict__ gm) {
    int g = threadIdx.x;
    if (g >= (NL + 1) * NQ) return;
    const float* th = theta + g * 3;
    float u00r, u00i, u01r, u01i;
    make_u(th[0], th[1], th[2], u00r, u00i, u01r, u01i);
    float* o = gm + g * 8;
    o[0] = u00r;  o[1] = u00i;  o[2] = u01r;  o[3] = u01i;
    o[4] = u01i;  o[5] = -u01r; o[6] = u00i;  o[7] = -u00r;
}

// State: amplitude k = lane*16 + r, r = 2*j + h.  fr[j]/fi[j] hold re/im of (r=2j, r=2j+1).
// Gate = [[a, b], [-conj(b), conj(a)]] given by 4 floats (ar,ai,br,bi).
template <int P>
__device__ __forceinline__ void apply_p(v2f fr[8], v2f fi[8],
                                        float ar, float ai, float br, float bi, int lane) {
    if constexpr (P == 0) {
        v2f c0r = { ar,  ar }, c0i = { ai, -ai };
        v2f c1r = { br, -br }, c1i = { bi,  bi };
#pragma unroll
        for (int j = 0; j < 8; ++j) {
            v2f av = fr[j], iv = fi[j];
            v2f srp = av.yx, sip = iv.yx;
            fr[j] = c0r * av - c0i * iv + c1r * srp - c1i * sip;
            fi[j] = c0r * iv + c0i * av + c1r * sip + c1i * srp;
        }
    } else if constexpr (P < 4) {
        constexpr int LJ = 1 << (P - 1);
        v2f a00r = sp(ar),  a00i = sp(ai),  a01r = sp(br), a01i = sp(bi);
        v2f a10r = sp(-br), a10i = sp(bi),  a11r = sp(ar), a11i = sp(-ai);
#pragma unroll
        for (int base = 0; base < 8; ++base) {
            if (base & LJ) continue;
            v2f a0r = fr[base], a0i = fi[base];
            v2f a1r = fr[base | LJ], a1i = fi[base | LJ];
            fr[base]      = a00r * a0r - a00i * a0i + a01r * a1r - a01i * a1i;
            fi[base]      = a00r * a0i + a00i * a0r + a01r * a1i + a01i * a1r;
            fr[base | LJ] = a10r * a0r - a10i * a0i + a11r * a1r - a11i * a1i;
            fi[base | LJ] = a10r * a0i + a10i * a0r + a11r * a1i + a11i * a1r;
        }
    } else if constexpr (P < 8) {
        // own-coefficient p = bit? conj(a) : a ; partner-coefficient q = bit? -conj(b) : b
        constexpr int M = 1 << (P - 4);
        const int bit = (lane >> (P - 4)) & 1;
        v2f pr = sp(ar), pi = sp(bit ? -ai : ai);
        v2f qr = sp(bit ? -br : br), qi = sp(bi);
#pragma unroll
        for (int j = 0; j < 8; ++j) {
            v2f ofr, ofi;
            ofr.x = lane_xor_direct<M>(fr[j].x);
            ofr.y = lane_xor_direct<M>(fr[j].y);
            ofi.x = lane_xor_direct<M>(fi[j].x);
            ofi.y = lane_xor_direct<M>(fi[j].y);
            v2f nr = pr * fr[j] - pi * fi[j] + qr * ofr - qi * ofi;
            v2f ni = pr * fi[j] + pi * fr[j] + qr * ofi + qi * ofr;
            fr[j] = nr;
            fi[j] = ni;
        }
    } else {
        // permlane swap gives both halves: result = cA*r0 + cB*r1, no per-value selects.
        // cA = hi? w10 : w00 = (hi? -br : ar, hi? bi : ai)
        // cB = hi? w11 : w01 = (hi? ar : br, hi? -ai : bi)
        constexpr int M = 1 << (P - 4);
        const bool hi = (lane & M) != 0;
        v2f cAr = sp(hi ? -br : ar), cAi = sp(hi ? bi : ai);
        v2f cBr = sp(hi ? ar : br),  cBi = sp(hi ? -ai : bi);
#pragma unroll
        for (int j = 0; j < 8; ++j) {
            float a0x, a1x, a0y, a1y, b0x, b1x, b0y, b1y;
            lane_swap_pair<M>(fr[j].x, a0x, a1x);
            lane_swap_pair<M>(fr[j].y, a0y, a1y);
            lane_swap_pair<M>(fi[j].x, b0x, b1x);
            lane_swap_pair<M>(fi[j].y, b0y, b1y);
            v2f A0r = { a0x, a0y }, A1r = { a1x, a1y };
            v2f A0i = { b0x, b0y }, A1i = { b1x, b1y };
            fr[j] = cAr * A0r - cAi * A0i + cBr * A1r - cBi * A1i;
            fi[j] = cAr * A0i + cAi * A0r + cBr * A1i + cBi * A1r;
        }
    }
}

// Fused gate: top row W = c*(g0..g3) + s*(g4..g7), 8 scalar FMAs.
#define GATE(qq, PP)                                                               \
    {                                                                              \
        const float* g = gl + (qq) * 8;                                            \
        float c = cc[qq], s = ss[qq];                                              \
        apply_p<PP>(fr, fi, c * g[0] + s * g[4], c * g[1] + s * g[5],              \
                            c * g[2] + s * g[6], c * g[3] + s * g[7], lane);       \
    }

// Layer-0 gate: W = V0 read directly (no sincos, no build).
#define GATE0(qq, PP)                                                              \
    {                                                                              \
        const float* g = gm + (qq) * 8;                                            \
        apply_p<PP>(fr, fi, g[0], g[1], g[2], g[3], lane);                         \
    }

__global__ void __launch_bounds__(64, 2) pqc_kernel(const float* __restrict__ x,
                                                    const float* __restrict__ lam,
                                                    const float* __restrict__ w,
                                                    const float* __restrict__ gm,
                                                    float* __restrict__ out, int B) {
    const int lane = threadIdx.x;
    const int b = blockIdx.x;

    v2f fr[8], fi[8];
#pragma unroll
    for (int j = 0; j < 8; ++j) { fr[j] = sp(0.f); fi[j] = sp(0.f); }
    if (lane == 0) fr[0].x = 1.f;

    // CZ-ring sign vectors and Z^n parity mask for this lane's 16 amplitudes.
    v2f sv[8];
    unsigned zmask = 0;
#pragma unroll
    for (int j = 0; j < 8; ++j) {
#pragma unroll
        for (int h = 0; h < 2; ++h) {
            int k = (lane << 4) | (2 * j + h);
            int par = (__popc(k & (k >> 1)) + ((k & (k >> 9)) & 1)) & 1;
            float s = __uint_as_float(0x3f800000u | ((unsigned)par << 31));
            if (h == 0) sv[j].x = s; else sv[j].y = s;
            zmask |= (unsigned)(__popc(k) & 1) << (2 * j + h);
        }
    }

    float xr[NQ];
#pragma unroll
    for (int q = 0; q < NQ; ++q) xr[q] = x[b * NQ + q];

    // Layer 0 (peeled): variational gates straight from V0, then CZ ring.
    GATE0(0, 9) GATE0(1, 8) GATE0(2, 7) GATE0(3, 6) GATE0(4, 5)
    GATE0(5, 4) GATE0(6, 3) GATE0(7, 2) GATE0(8, 1) GATE0(9, 0)
#pragma unroll
    for (int j = 0; j < 8; ++j) { fr[j] *= sv[j]; fi[j] *= sv[j]; }

    // Layers 1..NL: fused W = U_theta(l)*RX(x*lam(l-1)); CZ after each EXCEPT the last
    // (diag(+-1) before |amp|^2 is a no-op on the output).
#pragma clang loop unroll(disable)
    for (int l = 1; l <= NL; ++l) {
        const float* gl = gm + l * NQ * 8;
        const float* lm = lam + (l - 1) * NQ;
        float cc[NQ], ss[NQ];
#pragma unroll
        for (int q = 0; q < NQ; ++q)
            __sincosf(0.5f * xr[q] * lm[q], &ss[q], &cc[q]);
        GATE(0, 9) GATE(1, 8) GATE(2, 7) GATE(3, 6) GATE(4, 5)
        GATE(5, 4) GATE(6, 3) GATE(7, 2) GATE(8, 1) GATE(9, 0)
        if (l < NL) {
#pragma unroll
            for (int j = 0; j < 8; ++j) { fr[j] *= sv[j]; fi[j] *= sv[j]; }
        }
    }

    // <Z^n> = sum |amp|^2 * (-1)^popcount(k)
    v2f acc = sp(0.f);
#pragma unroll
    for (int j = 0; j < 8; ++j) {
        v2f zs;
        zs.x = __uint_as_float(0x3f800000u | (((zmask >> (2 * j)) & 1u) << 31));
        zs.y = __uint_as_float(0x3f800000u | (((zmask >> (2 * j + 1)) & 1u) << 31));
        acc += zs * (fr[j] * fr[j] + fi[j] * fi[j]);
    }
    float ez = acc.x + acc.y;
    ez += lane_xor<1>(ez, lane);
    ez += lane_xor<2>(ez, lane);
    ez += lane_xor<4>(ez, lane);
    ez += lane_xor<8>(ez, lane);
    ez += lane_xor<16>(ez, lane);
    ez += lane_xor<32>(ez, lane);

    if (lane == 0) {
        float l0 = ez * w[0], l1 = ez * w[1];   // BETA = 1
        float m = fmaxf(l0, l1);
        float e0 = __expf(l0 - m), e1 = __expf(l1 - m);
        float inv = 1.f / (e0 + e1);
        out[2 * b + 0] = e0 * inv;
        out[2 * b + 1] = e1 * inv;
    }
}

extern "C" void kernel_launch(void* const* d_in, const int* in_sizes, int n_in,
                              void* d_out, int out_size, void* d_ws, size_t ws_size,
                              hipStream_t stream) {
    const float* x     = (const float*)d_in[0];
    const float* theta = (const float*)d_in[1];
    const float* lam   = (const float*)d_in[2];
    const float* w     = (const float*)d_in[3];
    float* out = (float*)d_out;
    float* gm  = (float*)d_ws;                 // 60 gates * 8 floats = 1920 B

    const int B = in_sizes[0] / NQ;            // 2048
    hipLaunchKernelGGL(pqc_setup, dim3(1), dim3(64), 0, stream, theta, gm);
    hipLaunchKernelGGL(pqc_kernel, dim3(B), dim3(64), 0, stream,
                       x, lam, w, gm, out, B);
}